// Round 9
// baseline (376.687 us; speedup 1.0000x reference)
//
#include <hip/hip_runtime.h>
#include <math.h>

// Problem constants (fixed by the reference): N=8, B=4096, D=1024.
#define NN 8
#define BB 4096
#define DD 1024
#define LOG_2PI 1.8378770664093453f

// R8 (resubmit -- R8 bench never ran, GPU at capacity):
// High-occupancy x deep-MLP quadrant.
// R7b post-mortem: pipeline materialized (VGPR=192) but occupancy fell to
// 10.6% (2 waves/SIMD) -> BW stuck at 1.47 TB/s. R5/R6/R7b all traded MLP
// depth against waves; in-flight bytes/CU stayed ~50-100 KB. R8 keeps the
// register double-buffer (loads architecturally live -> regalloc can't
// collapse it, proven in R7b) but halves per-wave footprint: half-row per
// wave (8 elems/lane), ~85 VGPR capped at 102 via __launch_bounds__(256,5)
// -> 5 waves/SIMD = 20 waves/CU, 2.5x R7b, grid 2048 blocks (8/CU).
// Two waves share a row -> z pair-combine via 16 B LDS + one end barrier.

typedef float f32x4 __attribute__((ext_vector_type(4)));

__global__ __launch_bounds__(256, 5) void mpc_kernel(
    const float* __restrict__ means,
    const float* __restrict__ logsig,
    float* __restrict__ out_mean,
    float* __restrict__ out_logvar,
    float* __restrict__ out_logz)
{
    const int t    = threadIdx.x;
    const int wave = t >> 6;
    const int lane = t & 63;
    const int h    = (blockIdx.x << 2) + wave;      // half-row id, 8192 total
    const int row  = h >> 1;
    const size_t plane = (size_t)BB * DD;
    // element base for this lane: row*1024 + half*512 + lane*4
    const size_t base = (size_t)row * DD + (size_t)(h & 1) * 512 + (size_t)lane * 4;

    // ---- double-buffered plane-pair pipeline (4 loads = 4 KB/wave in flight) ----
    f32x4 bm[2][2], bl[2][2];
#pragma unroll
    for (int k = 0; k < 2; ++k) {
        bm[0][k] = *(const f32x4*)(means  + base + k * 256);
        bl[0][k] = *(const f32x4*)(logsig + base + k * 256);
    }

    float m1[8], v1[8], iv1[8];
    float z = 0.0f;

#pragma unroll
    for (int n = 0; n < NN; ++n) {
        // issue next plane-pair's 4 loads BEFORE computing current pair
        if (n + 1 < NN) {
            const size_t pb = (size_t)(n + 1) * plane + base;
#pragma unroll
            for (int k = 0; k < 2; ++k) {
                bm[(n + 1) & 1][k] = *(const f32x4*)(means  + pb + k * 256);
                bl[(n + 1) & 1][k] = *(const f32x4*)(logsig + pb + k * 256);
            }
        }
        // pin: prefetch issue stays above the compute of the current pair
        __builtin_amdgcn_sched_barrier(0);

#pragma unroll
        for (int k = 0; k < 2; ++k) {
            const float mk[4] = {bm[n & 1][k].x, bm[n & 1][k].y,
                                 bm[n & 1][k].z, bm[n & 1][k].w};
            const float lk[4] = {bl[n & 1][k].x, bl[n & 1][k].y,
                                 bl[n & 1][k].z, bl[n & 1][k].w};
#pragma unroll
            for (int j = 0; j < 4; ++j) {
                const int e = k * 4 + j;
                if (n == 0) {
                    m1[e]  = mk[j];
                    v1[e]  = __expf(lk[j]);
                    iv1[e] = __expf(-lk[j]);
                } else {
                    float v2   = __expf(lk[j]);
                    float iv2  = __expf(-lk[j]);
                    float s    = v1[e] + v2 + 1e-6f;
                    float d    = m1[e] - mk[j];
                    z += d * d * __builtin_amdgcn_rcpf(s) + __logf(s);
                    float ivn  = iv1[e] + iv2;
                    float cv   = __builtin_amdgcn_rcpf(ivn);
                    m1[e]  = cv * (m1[e] * iv1[e] + mk[j] * iv2);
                    v1[e]  = cv;
                    iv1[e] = ivn;
                }
            }
        }
    }

    // ---- outputs (nontemporal: don't evict LLC-resident inputs) ----
#pragma unroll
    for (int k = 0; k < 2; ++k) {
        f32x4 om = {m1[k*4+0], m1[k*4+1], m1[k*4+2], m1[k*4+3]};
        f32x4 ol = {__logf(v1[k*4+0]), __logf(v1[k*4+1]),
                    __logf(v1[k*4+2]), __logf(v1[k*4+3])};
        __builtin_nontemporal_store(om, (f32x4*)(out_mean   + base + k * 256));
        __builtin_nontemporal_store(ol, (f32x4*)(out_logvar + base + k * 256));
    }

    // ---- z reduction: wave-local shuffle, then combine the two half-rows ----
#pragma unroll
    for (int o = 32; o > 0; o >>= 1)
        z += __shfl_down(z, o, 64);

    __shared__ float sz[4];
    if (lane == 0) sz[wave] = z;
    __syncthreads();
    // waves (0,1) share row (block*2), waves (2,3) share row (block*2+1)
    if (lane == 0 && (wave & 1) == 0) {
        float total = sz[wave] + sz[wave + 1];
        out_logz[row] = -0.5f * (total + (float)((NN - 1) * DD) * LOG_2PI);
    }
}

extern "C" void kernel_launch(void* const* d_in, const int* in_sizes, int n_in,
                              void* d_out, int out_size, void* d_ws, size_t ws_size,
                              hipStream_t stream) {
    const float* means  = (const float*)d_in[0];
    const float* logsig = (const float*)d_in[1];
    float* out = (float*)d_out;
    float* out_mean   = out;
    float* out_logvar = out + (size_t)BB * DD;
    float* out_logz   = out + 2 * (size_t)BB * DD;
    mpc_kernel<<<BB * 2 / 4, 256, 0, stream>>>(means, logsig, out_mean, out_logvar, out_logz);
}

// Round 11
// 334.801 us; speedup vs baseline: 1.1251x; 1.1251x over previous
//
#include <hip/hip_runtime.h>
#include <math.h>

// Problem constants (fixed by the reference): N=8, B=4096, D=1024.
#define NN 8
#define BB 4096
#define DD 1024
#define LOG_2PI 1.8378770664093453f

// R9 (resubmit -- bench never ran, GPU at capacity):
// R8 with the register cap relaxed (256,5)->(256,4).
// R8 post-mortem: the 102-VGPR cap made the compiler SPILL the double-buffer
// + scan state to scratch (VGPR=48; WRITE_SIZE 286 MB = 32 MB output + ~254 MB
// scratch writeback; FETCH up to 250 MB; dur 190 us). But occupancy 47% drove
// the fabric to 2.9 TB/s -- concurrency IS the limiter, the bandwidth was just
// wasted on spill traffic. R9 keeps the half-row/wave deep-MLP structure
// (proven pipeline, R7b) at a 128-VGPR budget: ~90 VGPR needed -> fits, no
// spill, 4 waves/SIMD = 16 waves/CU (2x R7b).

typedef float f32x4 __attribute__((ext_vector_type(4)));

__global__ __launch_bounds__(256, 4) void mpc_kernel(
    const float* __restrict__ means,
    const float* __restrict__ logsig,
    float* __restrict__ out_mean,
    float* __restrict__ out_logvar,
    float* __restrict__ out_logz)
{
    const int t    = threadIdx.x;
    const int wave = t >> 6;
    const int lane = t & 63;
    const int h    = (blockIdx.x << 2) + wave;      // half-row id, 8192 total
    const int row  = h >> 1;
    const size_t plane = (size_t)BB * DD;
    // element base for this lane: row*1024 + half*512 + lane*4
    const size_t base = (size_t)row * DD + (size_t)(h & 1) * 512 + (size_t)lane * 4;

    // ---- double-buffered plane-pair pipeline (4 loads = 4 KB/wave in flight) ----
    f32x4 bm[2][2], bl[2][2];
#pragma unroll
    for (int k = 0; k < 2; ++k) {
        bm[0][k] = *(const f32x4*)(means  + base + k * 256);
        bl[0][k] = *(const f32x4*)(logsig + base + k * 256);
    }

    float m1[8], v1[8], iv1[8];
    float z = 0.0f;

#pragma unroll
    for (int n = 0; n < NN; ++n) {
        // issue next plane-pair's 4 loads BEFORE computing current pair
        if (n + 1 < NN) {
            const size_t pb = (size_t)(n + 1) * plane + base;
#pragma unroll
            for (int k = 0; k < 2; ++k) {
                bm[(n + 1) & 1][k] = *(const f32x4*)(means  + pb + k * 256);
                bl[(n + 1) & 1][k] = *(const f32x4*)(logsig + pb + k * 256);
            }
        }
        // pin: prefetch issue stays above the compute of the current pair
        __builtin_amdgcn_sched_barrier(0);

#pragma unroll
        for (int k = 0; k < 2; ++k) {
            const float mk[4] = {bm[n & 1][k].x, bm[n & 1][k].y,
                                 bm[n & 1][k].z, bm[n & 1][k].w};
            const float lk[4] = {bl[n & 1][k].x, bl[n & 1][k].y,
                                 bl[n & 1][k].z, bl[n & 1][k].w};
#pragma unroll
            for (int j = 0; j < 4; ++j) {
                const int e = k * 4 + j;
                if (n == 0) {
                    m1[e]  = mk[j];
                    v1[e]  = __expf(lk[j]);
                    iv1[e] = __expf(-lk[j]);
                } else {
                    float v2   = __expf(lk[j]);
                    float iv2  = __expf(-lk[j]);
                    float s    = v1[e] + v2 + 1e-6f;
                    float d    = m1[e] - mk[j];
                    z += d * d * __builtin_amdgcn_rcpf(s) + __logf(s);
                    float ivn  = iv1[e] + iv2;
                    float cv   = __builtin_amdgcn_rcpf(ivn);
                    m1[e]  = cv * (m1[e] * iv1[e] + mk[j] * iv2);
                    v1[e]  = cv;
                    iv1[e] = ivn;
                }
            }
        }
    }

    // ---- outputs (nontemporal: don't evict LLC-resident inputs) ----
#pragma unroll
    for (int k = 0; k < 2; ++k) {
        f32x4 om = {m1[k*4+0], m1[k*4+1], m1[k*4+2], m1[k*4+3]};
        f32x4 ol = {__logf(v1[k*4+0]), __logf(v1[k*4+1]),
                    __logf(v1[k*4+2]), __logf(v1[k*4+3])};
        __builtin_nontemporal_store(om, (f32x4*)(out_mean   + base + k * 256));
        __builtin_nontemporal_store(ol, (f32x4*)(out_logvar + base + k * 256));
    }

    // ---- z reduction: wave-local shuffle, then combine the two half-rows ----
#pragma unroll
    for (int o = 32; o > 0; o >>= 1)
        z += __shfl_down(z, o, 64);

    __shared__ float sz[4];
    if (lane == 0) sz[wave] = z;
    __syncthreads();
    // waves (0,1) share row (block*2), waves (2,3) share row (block*2+1)
    if (lane == 0 && (wave & 1) == 0) {
        float total = sz[wave] + sz[wave + 1];
        out_logz[row] = -0.5f * (total + (float)((NN - 1) * DD) * LOG_2PI);
    }
}

extern "C" void kernel_launch(void* const* d_in, const int* in_sizes, int n_in,
                              void* d_out, int out_size, void* d_ws, size_t ws_size,
                              hipStream_t stream) {
    const float* means  = (const float*)d_in[0];
    const float* logsig = (const float*)d_in[1];
    float* out = (float*)d_out;
    float* out_mean   = out;
    float* out_logvar = out + (size_t)BB * DD;
    float* out_logz   = out + 2 * (size_t)BB * DD;
    mpc_kernel<<<BB * 2 / 4, 256, 0, stream>>>(means, logsig, out_mean, out_logvar, out_logz);
}

// Round 12
// 287.305 us; speedup vs baseline: 1.3111x; 1.1653x over previous
//
#include <hip/hip_runtime.h>
#include <math.h>

// Problem constants (fixed by the reference): N=8, B=4096, D=1024.
#define NN 8
#define BB 4096
#define DD 1024
#define LOG_2PI 1.8378770664093453f

// R10: shrink live state; UNCAP the allocator.
// R8/R9 post-mortem: both __launch_bounds__ min-wave caps ((256,5)->VGPR48,
// (256,4)->VGPR64) made the allocator spill the pipeline to scratch
// (WRITE_SIZE 286/178 MB vs 33 MB of real output). R7b with a plain
// __launch_bounds__(256) allocated exactly what was needed, zero spill.
// Occupancy 39-47% demonstrably drives 2.5-2.9 TB/s -- the BW is there, the
// spill is eating it. So: (1) drop v1[8] (v1==rcp(iv1); recompute per step,
// logvar = -log(iv1)) -> live state ~60 VGPR; (2) no min-waves floor ->
// allocator picks ~60-100, no spill, 4-8 waves/SIMD.

typedef float f32x4 __attribute__((ext_vector_type(4)));

__global__ __launch_bounds__(256) void mpc_kernel(
    const float* __restrict__ means,
    const float* __restrict__ logsig,
    float* __restrict__ out_mean,
    float* __restrict__ out_logvar,
    float* __restrict__ out_logz)
{
    const int t    = threadIdx.x;
    const int wave = t >> 6;
    const int lane = t & 63;
    const int h    = (blockIdx.x << 2) + wave;      // half-row id, 8192 total
    const int row  = h >> 1;
    const size_t plane = (size_t)BB * DD;
    // element base for this lane: row*1024 + half*512 + lane*4
    const size_t base = (size_t)row * DD + (size_t)(h & 1) * 512 + (size_t)lane * 4;

    // ---- double-buffered plane-pair pipeline (4 loads = 4 KB/wave in flight) ----
    f32x4 bm[2][2], bl[2][2];
#pragma unroll
    for (int k = 0; k < 2; ++k) {
        bm[0][k] = *(const f32x4*)(means  + base + k * 256);
        bl[0][k] = *(const f32x4*)(logsig + base + k * 256);
    }

    float m1[8], iv1[8];    // v1 not stored: v1 == rcp(iv1)
    float z = 0.0f;

#pragma unroll
    for (int n = 0; n < NN; ++n) {
        // issue next plane-pair's 4 loads BEFORE computing current pair
        if (n + 1 < NN) {
            const size_t pb = (size_t)(n + 1) * plane + base;
#pragma unroll
            for (int k = 0; k < 2; ++k) {
                bm[(n + 1) & 1][k] = *(const f32x4*)(means  + pb + k * 256);
                bl[(n + 1) & 1][k] = *(const f32x4*)(logsig + pb + k * 256);
            }
        }
        // pin: prefetch issue stays above the compute of the current pair
        __builtin_amdgcn_sched_barrier(0);

#pragma unroll
        for (int k = 0; k < 2; ++k) {
            const float mk[4] = {bm[n & 1][k].x, bm[n & 1][k].y,
                                 bm[n & 1][k].z, bm[n & 1][k].w};
            const float lk[4] = {bl[n & 1][k].x, bl[n & 1][k].y,
                                 bl[n & 1][k].z, bl[n & 1][k].w};
#pragma unroll
            for (int j = 0; j < 4; ++j) {
                const int e = k * 4 + j;
                if (n == 0) {
                    m1[e]  = mk[j];
                    iv1[e] = __expf(-lk[j]);
                } else {
                    float v2   = __expf(lk[j]);
                    float iv2  = __expf(-lk[j]);
                    float v1e  = __builtin_amdgcn_rcpf(iv1[e]);
                    float s    = v1e + v2 + 1e-6f;
                    float d    = m1[e] - mk[j];
                    z += d * d * __builtin_amdgcn_rcpf(s) + __logf(s);
                    float ivn  = iv1[e] + iv2;
                    float cv   = __builtin_amdgcn_rcpf(ivn);
                    m1[e]  = cv * (m1[e] * iv1[e] + mk[j] * iv2);
                    iv1[e] = ivn;
                }
            }
        }
    }

    // ---- outputs (nontemporal: don't evict LLC-resident inputs) ----
    // logvar = log(v1) = log(rcp(iv1)) = -log(iv1)
#pragma unroll
    for (int k = 0; k < 2; ++k) {
        f32x4 om = {m1[k*4+0], m1[k*4+1], m1[k*4+2], m1[k*4+3]};
        f32x4 ol = {-__logf(iv1[k*4+0]), -__logf(iv1[k*4+1]),
                    -__logf(iv1[k*4+2]), -__logf(iv1[k*4+3])};
        __builtin_nontemporal_store(om, (f32x4*)(out_mean   + base + k * 256));
        __builtin_nontemporal_store(ol, (f32x4*)(out_logvar + base + k * 256));
    }

    // ---- z reduction: wave-local shuffle, then combine the two half-rows ----
#pragma unroll
    for (int o = 32; o > 0; o >>= 1)
        z += __shfl_down(z, o, 64);

    __shared__ float sz[4];
    if (lane == 0) sz[wave] = z;
    __syncthreads();
    // waves (0,1) share row (block*2), waves (2,3) share row (block*2+1)
    if (lane == 0 && (wave & 1) == 0) {
        float total = sz[wave] + sz[wave + 1];
        out_logz[row] = -0.5f * (total + (float)((NN - 1) * DD) * LOG_2PI);
    }
}

extern "C" void kernel_launch(void* const* d_in, const int* in_sizes, int n_in,
                              void* d_out, int out_size, void* d_ws, size_t ws_size,
                              hipStream_t stream) {
    const float* means  = (const float*)d_in[0];
    const float* logsig = (const float*)d_in[1];
    float* out = (float*)d_out;
    float* out_mean   = out;
    float* out_logvar = out + (size_t)BB * DD;
    float* out_logz   = out + 2 * (size_t)BB * DD;
    mpc_kernel<<<BB * 2 / 4, 256, 0, stream>>>(means, logsig, out_mean, out_logvar, out_logz);
}